// Round 8
// baseline (575.401 us; speedup 1.0000x reference)
//
#include <hip/hip_runtime.h>
#include <hip/hip_bf16.h>

typedef unsigned short u16;
typedef __attribute__((ext_vector_type(8))) __bf16 bf16x8;
typedef __attribute__((ext_vector_type(4))) float f32x4;
typedef __attribute__((ext_vector_type(8))) unsigned short ushort8;

#define GM 8192
#define GN 4096
#define GK 4096
#define NT (GK / 64)  // 64 K-tiles of BK=64

__device__ __forceinline__ u16 f2bf(float f) {
  unsigned u = __float_as_uint(f);
  u += 0x7fffu + ((u >> 16) & 1u);
  return (u16)(u >> 16);
}

// ---- kernel 1: W_eff = bf16(W + 2 * (B @ A))   [4096][4096]
__global__ void build_weff(const float* __restrict__ W,
                           const float* __restrict__ lA,
                           const float* __restrict__ lB,
                           u16* __restrict__ Weff) {
  const int o = blockIdx.x;
  float b[8];
#pragma unroll
  for (int r = 0; r < 8; ++r) b[r] = 2.0f * lB[o * 8 + r];
  const float* wrow = W + (size_t)o * GK;
  u16* orow = Weff + (size_t)o * GK;
  for (int d = threadIdx.x * 4; d < GK; d += blockDim.x * 4) {
    float4 w = *reinterpret_cast<const float4*>(wrow + d);
    float a0 = w.x, a1 = w.y, a2 = w.z, a3 = w.w;
#pragma unroll
    for (int r = 0; r < 8; ++r) {
      float4 a = *reinterpret_cast<const float4*>(lA + r * GK + d);
      a0 += b[r] * a.x; a1 += b[r] * a.y; a2 += b[r] * a.z; a3 += b[r] * a.w;
    }
    ushort4 p;
    p.x = f2bf(a0); p.y = f2bf(a1); p.z = f2bf(a2); p.w = f2bf(a3);
    *reinterpret_cast<ushort4*>(orow + d) = p;
  }
}

// ---- kernel 2: x f32 -> bf16
__global__ void cvt_bf16(const float* __restrict__ x, u16* __restrict__ xb) {
  const size_t i = ((size_t)blockIdx.x * blockDim.x + threadIdx.x) * 8;
  float4 v0 = *reinterpret_cast<const float4*>(x + i);
  float4 v1 = *reinterpret_cast<const float4*>(x + i + 4);
  ushort8 o;
  o[0] = f2bf(v0.x); o[1] = f2bf(v0.y); o[2] = f2bf(v0.z); o[3] = f2bf(v0.w);
  o[4] = f2bf(v1.x); o[5] = f2bf(v1.y); o[6] = f2bf(v1.z); o[7] = f2bf(v1.w);
  *reinterpret_cast<ushort8*>(xb + i) = o;
}

// ---- kernel 3: 256x256-tile GEMM, C[m][n] = sum_k A[m][k]*B[n][k]
// R8: one-phase-lag JIT read pipeline (m201 mechanism decoded).
// Quadrants: P0(lo,b0) P1(lo,b1) P2(hi,b1) P3(hi,b0).
// Reads (always ONE phase before consumption, issued pre-barrier):
//   P3(t-1): af_lo(t)[8] + b0(t)[4];  P0(t): bfr1(t)[4];  P1(t): af_hi(t)[8].
// Stages: P0(t)->A0(t+1); P1(t)->A1,B0,B1(t+1)  (region-safe: each region's
//   last ds_read serviced before a barrier that precedes the stage issue).
// ONE vmcnt(0) per tile at P2-end (post-MFMA): newest stage ~1.2 phases old;
// the following BAR gates P3's cross-wave reads of all four t+1 halves.
// b0 frag set spans 5 phases -> two sets (b0A/b0B), loop unrolled x2.
// 3-bit LDS swizzle (conflict-free, R3) + XCD swizzle kept.
__device__ __forceinline__ void gload16(const u16* g, u16* l) {
  __builtin_amdgcn_global_load_lds(
      (const __attribute__((address_space(1))) void*)g,
      (__attribute__((address_space(3))) void*)l, 16, 0, 0);
}

#define BAR()                                  \
  do {                                         \
    asm volatile("" ::: "memory");             \
    __builtin_amdgcn_s_barrier();              \
    asm volatile("" ::: "memory");             \
  } while (0)

__global__ __launch_bounds__(512, 2) void gemm256(const u16* __restrict__ Ab,
                                                  const u16* __restrict__ Bb,
                                                  float* __restrict__ C) {
  // [buf][0=A,1=B][row*64 + k], 2*2*16384*2B = 128 KiB
  __shared__ u16 lds[2][2][256 * 64];

  const int tid = threadIdx.x;
  const int wv = tid >> 6;
  const int l = tid & 63;

  // XCD-aware swizzle: 512 blocks, 512 % 8 == 0 -> simple bijective form
  const int nwg = gridDim.x;
  const int cpx = nwg >> 3;
  const int wg = ((int)blockIdx.x & 7) * cpx + ((int)blockIdx.x >> 3);
  const int tm = wg >> 4;   // GN/256 = 16 tiles in N
  const int tn = wg & 15;

  const int wr = wv >> 2;   // 0..1  (M split)
  const int wc = wv & 3;    // 0..3  (N split)

  // --- staging constants ---
  const int srow = (wv << 3) + (l >> 3);
  const int srl = ((wv & 1) << 3) | (l >> 3);          // row bits 0..3
  const int skel = ((l & 7) << 3) ^ ((srl & 0xE) << 2);
  const u16* aG = Ab + (size_t)(tm * 256) * GK;
  const u16* bG = Bb + (size_t)(tn * 256) * GK;

  // --- reader constants ---
  const int frow = l & 15;
  const int fksw = ((l >> 4) << 3) ^ ((frow & 0xE) << 2);
  const int arow = wr * 128 + frow;
  const int brow = wc * 64 + frow;

  // stage half-tile: th = K-tile, r: 0=A0,1=A1,2=B0,3=B1  (2 x gload16/wave)
  auto STAGE = [&](int th, int r) {
    const int k0 = th << 6;
    const u16* src = (r < 2 ? aG : bG) +
                     (size_t)((r & 1) * 128 + srow) * GK + k0 + skel;
    u16* dst = &lds[th & 1][r >> 1][(r & 1) * 8192 + wv * 512];
#pragma unroll
    for (int j = 0; j < 2; ++j)
      gload16(src + (size_t)(j * 64) * GK, dst + j * 4096);
  };

  f32x4 acc[8][4] = {};
  bf16x8 af_lo[4][2], af_hi[4][2], bfr1[2][2], b0A[2][2], b0B[2][2];

// read helpers (macros keep all indices compile-time constant)
#define RD_AF(dst, Abase, moff)                                        \
  _Pragma("unroll") for (int m = 0; m < 4; ++m)                        \
  _Pragma("unroll") for (int s = 0; s < 2; ++s)                        \
      dst[m][s] = *reinterpret_cast<const bf16x8*>(                    \
          (Abase) + (arow + (m + (moff)) * 16) * 64 + (fksw ^ (s << 5)));
#define RD_B(dst, Bbase, noff)                                         \
  _Pragma("unroll") for (int n = 0; n < 2; ++n)                        \
  _Pragma("unroll") for (int s = 0; s < 2; ++s)                        \
      dst[n][s] = *reinterpret_cast<const bf16x8*>(                    \
          (Bbase) + (brow + (n + (noff)) * 16) * 64 + (fksw ^ (s << 5)));
#define MFMA8(AF, BF, mo, no)                                          \
  _Pragma("unroll") for (int m = 0; m < 4; ++m)                        \
  _Pragma("unroll") for (int n = 0; n < 2; ++n)                        \
  _Pragma("unroll") for (int s = 0; s < 2; ++s)                        \
      acc[(mo) + m][(no) + n] = __builtin_amdgcn_mfma_f32_16x16x32_bf16( \
          AF[m][s], BF[n][s], acc[(mo) + m][(no) + n], 0, 0, 0);

#define BODY(T, ACUR, BCUR, ANXT, BNXT, OLDB, NEWB)                    \
  {                                                                    \
    /* P0: reads bfr1(T); stage A0(T+1) */                             \
    RD_B(bfr1, BCUR, 2);                                               \
    if ((T) + 1 < NT) STAGE((T) + 1, 0);                               \
    BAR();                                                             \
    __builtin_amdgcn_s_setprio(1);                                     \
    MFMA8(af_lo, OLDB, 0, 0);                                          \
    __builtin_amdgcn_s_setprio(0);                                     \
    BAR();                                                             \
    /* P1: reads af_hi(T); stage A1,B0,B1(T+1) */                      \
    RD_AF(af_hi, ACUR, 4);                                             \
    if ((T) + 1 < NT) {                                                \
      STAGE((T) + 1, 1); STAGE((T) + 1, 2); STAGE((T) + 1, 3);         \
    }                                                                  \
    BAR();                                                             \
    __builtin_amdgcn_s_setprio(1);                                     \
    MFMA8(af_lo, bfr1, 0, 2);                                          \
    __builtin_amdgcn_s_setprio(0);                                     \
    BAR();                                                             \
    /* P2: pure MFMA; vmcnt(0) gates next phase's reads of tile T+1 */ \
    __builtin_amdgcn_s_setprio(1);                                     \
    MFMA8(af_hi, bfr1, 4, 2);                                          \
    __builtin_amdgcn_s_setprio(0);                                     \
    asm volatile("s_waitcnt vmcnt(0)" ::: "memory");                   \
    BAR();                                                             \
    /* P3: reads af_lo(T+1) + NEWB(T+1) */                             \
    if ((T) + 1 < NT) {                                                \
      RD_AF(af_lo, ANXT, 0);                                           \
      RD_B(NEWB, BNXT, 0);                                             \
    }                                                                  \
    BAR();                                                             \
    __builtin_amdgcn_s_setprio(1);                                     \
    MFMA8(af_hi, OLDB, 4, 0);                                          \
    __builtin_amdgcn_s_setprio(0);                                     \
    BAR();                                                             \
  }

  // prologue: stage tile 0, drain, pre-read P0(0)'s operands
  STAGE(0, 0); STAGE(0, 1); STAGE(0, 2); STAGE(0, 3);
  asm volatile("s_waitcnt vmcnt(0)" ::: "memory");
  BAR();
  RD_AF(af_lo, (&lds[0][0][0]), 0);
  RD_B(b0A, (&lds[0][1][0]), 0);

  for (int t = 0; t < NT; t += 2) {
    BODY(t, (&lds[0][0][0]), (&lds[0][1][0]), (&lds[1][0][0]),
         (&lds[1][1][0]), b0A, b0B);
    BODY(t + 1, (&lds[1][0][0]), (&lds[1][1][0]), (&lds[0][0][0]),
         (&lds[0][1][0]), b0B, b0A);
  }

  // epilogue: C/D layout col = l&15, row = 4*(l>>4)+j
  const int orow = tm * 256 + wr * 128 + ((l >> 4) << 2);
  const int ocol = tn * 256 + wc * 64 + (l & 15);
#pragma unroll
  for (int m = 0; m < 8; ++m)
#pragma unroll
    for (int n = 0; n < 4; ++n) {
      float* cp = C + (size_t)(orow + m * 16) * GN + (ocol + n * 16);
#pragma unroll
      for (int j = 0; j < 4; ++j) cp[(size_t)j * GN] = acc[m][n][j];
    }
}

extern "C" void kernel_launch(void* const* d_in, const int* in_sizes, int n_in,
                              void* d_out, int out_size, void* d_ws, size_t ws_size,
                              hipStream_t stream) {
  const float* x  = (const float*)d_in[0];
  const float* W  = (const float*)d_in[1];
  const float* lA = (const float*)d_in[2];
  const float* lB = (const float*)d_in[3];
  float* out = (float*)d_out;

  u16* weff = (u16*)d_ws;
  u16* xb = (u16*)((char*)d_ws + (size_t)GN * GK * sizeof(u16));

  build_weff<<<GN, 256, 0, stream>>>(W, lA, lB, weff);
  cvt_bf16<<<(size_t)GM * GK / (256 * 8), 256, 0, stream>>>(x, xb);
  gemm256<<<(GM / 256) * (GN / 256), 512, 0, stream>>>(xb, weff, out);
}

// Round 9
// 293.523 us; speedup vs baseline: 1.9603x; 1.9603x over previous
//
#include <hip/hip_runtime.h>
#include <hip/hip_bf16.h>

typedef unsigned short u16;
typedef __attribute__((ext_vector_type(8))) __bf16 bf16x8;
typedef __attribute__((ext_vector_type(4))) float f32x4;
typedef __attribute__((ext_vector_type(8))) unsigned short ushort8;

#define GM 8192
#define GN 4096
#define GK 4096
#define NT (GK / 64)  // 64 K-tiles of BK=64

__device__ __forceinline__ u16 f2bf(float f) {
  unsigned u = __float_as_uint(f);
  u += 0x7fffu + ((u >> 16) & 1u);
  return (u16)(u >> 16);
}

// ---- kernel 1: W_eff = bf16(W + 2 * (B @ A))   [4096][4096]
__global__ void build_weff(const float* __restrict__ W,
                           const float* __restrict__ lA,
                           const float* __restrict__ lB,
                           u16* __restrict__ Weff) {
  const int o = blockIdx.x;
  float b[8];
#pragma unroll
  for (int r = 0; r < 8; ++r) b[r] = 2.0f * lB[o * 8 + r];
  const float* wrow = W + (size_t)o * GK;
  u16* orow = Weff + (size_t)o * GK;
  for (int d = threadIdx.x * 4; d < GK; d += blockDim.x * 4) {
    float4 w = *reinterpret_cast<const float4*>(wrow + d);
    float a0 = w.x, a1 = w.y, a2 = w.z, a3 = w.w;
#pragma unroll
    for (int r = 0; r < 8; ++r) {
      float4 a = *reinterpret_cast<const float4*>(lA + r * GK + d);
      a0 += b[r] * a.x; a1 += b[r] * a.y; a2 += b[r] * a.z; a3 += b[r] * a.w;
    }
    ushort4 p;
    p.x = f2bf(a0); p.y = f2bf(a1); p.z = f2bf(a2); p.w = f2bf(a3);
    *reinterpret_cast<ushort4*>(orow + d) = p;
  }
}

// ---- kernel 2: x f32 -> bf16
__global__ void cvt_bf16(const float* __restrict__ x, u16* __restrict__ xb) {
  const size_t i = ((size_t)blockIdx.x * blockDim.x + threadIdx.x) * 8;
  float4 v0 = *reinterpret_cast<const float4*>(x + i);
  float4 v1 = *reinterpret_cast<const float4*>(x + i + 4);
  ushort8 o;
  o[0] = f2bf(v0.x); o[1] = f2bf(v0.y); o[2] = f2bf(v0.z); o[3] = f2bf(v0.w);
  o[4] = f2bf(v1.x); o[5] = f2bf(v1.y); o[6] = f2bf(v1.z); o[7] = f2bf(v1.w);
  *reinterpret_cast<ushort8*>(xb + i) = o;
}

// ---- kernel 3: 256x256-tile GEMM, C[m][n] = sum_k A[m][k]*B[n][k]
// R9: one-phase-lag, register-neutral (frags = R7's 96 VGPR + 128 acc).
// Phases (1 barrier each): P0: rd b01+b23(t)[8], stage B1(t+1) | Q0=lo*b01
//   P1: rd af_hi(t)[8], stage B0(t+2), vmcnt(4) | Q1=lo*b23
//   P2: rd af_lo(t+1)[8] (from next buf), stage A0(t+2) | Q2=hi*b23
//   P3: stage A1(t+2), vmcnt(6) | Q3=hi*b01
// Every operand except b01 is read >=1 phase before use; partial lgkmcnt
// after each barrier (4/8/8/-) never waits on prefetch reads.
// vmcnt ledger (2 gloads/stage, in-order): vmcnt(4)@P1 retires A0,A1(t+1)
// (needed by P2 reads); vmcnt(6)@P3 retires B1(t+1) (needed by P0(t+1)).
// Max 8 loads in flight. No conditionals in loop (stages clamp k0; tail
// reads harmless). 3-bit LDS swizzle (conflict-free, R3) + XCD swizzle.
__device__ __forceinline__ void gload16(const u16* g, u16* l) {
  __builtin_amdgcn_global_load_lds(
      (const __attribute__((address_space(1))) void*)g,
      (__attribute__((address_space(3))) void*)l, 16, 0, 0);
}

#define BAR()                                  \
  do {                                         \
    asm volatile("" ::: "memory");             \
    __builtin_amdgcn_s_barrier();              \
    asm volatile("" ::: "memory");             \
  } while (0)

__global__ __launch_bounds__(512, 2) void gemm256(const u16* __restrict__ Ab,
                                                  const u16* __restrict__ Bb,
                                                  float* __restrict__ C) {
  // [buf][0=A,1=B][row*64 + k], 2*2*16384*2B = 128 KiB
  __shared__ u16 lds[2][2][256 * 64];

  const int tid = threadIdx.x;
  const int wv = tid >> 6;
  const int l = tid & 63;

  // XCD-aware swizzle: 512 blocks, 512 % 8 == 0 -> simple bijective form
  const int nwg = gridDim.x;
  const int cpx = nwg >> 3;
  const int wg = ((int)blockIdx.x & 7) * cpx + ((int)blockIdx.x >> 3);
  const int tm = wg >> 4;   // GN/256 = 16 tiles in N
  const int tn = wg & 15;

  const int wr = wv >> 2;   // 0..1  (M split)
  const int wc = wv & 3;    // 0..3  (N split)

  // --- staging constants ---
  const int srow = (wv << 3) + (l >> 3);
  const int srl = ((wv & 1) << 3) | (l >> 3);          // row bits 0..3
  const int skel = ((l & 7) << 3) ^ ((srl & 0xE) << 2);
  const u16* aG = Ab + (size_t)(tm * 256) * GK;
  const u16* bG = Bb + (size_t)(tn * 256) * GK;

  // --- reader constants ---
  const int frow = l & 15;
  const int fksw = ((l >> 4) << 3) ^ ((frow & 0xE) << 2);
  const int arow = wr * 128 + frow;
  const int brow = wc * 64 + frow;

  // stage half-tile: th = K-tile, r: 0=A0,1=A1,2=B0,3=B1  (2 x gload16/wave)
  auto STAGE = [&](int th, int r) {
    const int tc = th < NT ? th : NT - 1;  // clamp k (tail; LDS region safe)
    const int k0 = tc << 6;
    const u16* src = (r < 2 ? aG : bG) +
                     (size_t)((r & 1) * 128 + srow) * GK + k0 + skel;
    u16* dst = &lds[th & 1][r >> 1][(r & 1) * 8192 + wv * 512];
#pragma unroll
    for (int j = 0; j < 2; ++j)
      gload16(src + (size_t)(j * 64) * GK, dst + j * 4096);
  };

  f32x4 acc[8][4] = {};
  bf16x8 af_lo[4][2], af_hi[4][2], bfr[4][2];

#define RD_AF(dst, Abase, moff)                                        \
  _Pragma("unroll") for (int m = 0; m < 4; ++m)                        \
  _Pragma("unroll") for (int s = 0; s < 2; ++s)                        \
      dst[m][s] = *reinterpret_cast<const bf16x8*>(                    \
          (Abase) + (arow + (m + (moff)) * 16) * 64 + (fksw ^ (s << 5)));
#define RD_B2(n0, Bbase)                                               \
  _Pragma("unroll") for (int n = 0; n < 2; ++n)                        \
  _Pragma("unroll") for (int s = 0; s < 2; ++s)                        \
      bfr[(n0) + n][s] = *reinterpret_cast<const bf16x8*>(             \
          (Bbase) + (brow + ((n0) + n) * 16) * 64 + (fksw ^ (s << 5)));
#define MFMA16(AF, nb, mo, no)                                         \
  _Pragma("unroll") for (int m = 0; m < 4; ++m)                        \
  _Pragma("unroll") for (int n = 0; n < 2; ++n)                        \
  _Pragma("unroll") for (int s = 0; s < 2; ++s)                        \
      acc[(mo) + m][(no) + n] = __builtin_amdgcn_mfma_f32_16x16x32_bf16( \
          AF[m][s], bfr[(nb) + n][s], acc[(mo) + m][(no) + n], 0, 0, 0);

  // prologue: tile0 all 4 halves + A0,A1,B0 of tile1 (B1(1) staged @P0(0))
  STAGE(0, 0); STAGE(0, 1); STAGE(0, 2); STAGE(0, 3);
  STAGE(1, 0); STAGE(1, 1); STAGE(1, 2);
  asm volatile("s_waitcnt vmcnt(0)" ::: "memory");
  BAR();
  RD_AF(af_lo, (&lds[0][0][0]), 0);  // af_lo(0) (steady: read @P2(t-1))

  for (int t = 0; t < NT; ++t) {
    const u16* A = &lds[t & 1][0][0];
    const u16* B = &lds[t & 1][1][0];
    const u16* Anx = &lds[(t + 1) & 1][0][0];

    // ---- P0: rd b01(t)+b23(t); stage B1(t+1) ----
    RD_B2(0, B);
    RD_B2(2, B);
    STAGE(t + 1, 3);
    BAR();
    asm volatile("s_waitcnt lgkmcnt(4)" ::: "memory");  // b01 landed
    __builtin_amdgcn_s_setprio(1);
    MFMA16(af_lo, 0, 0, 0);  // Q0: m0-3 x n0-1
    __builtin_amdgcn_s_setprio(0);

    // ---- P1: rd af_hi(t); stage B0(t+2); vmcnt(4) ----
    RD_AF(af_hi, A, 4);
    STAGE(t + 2, 2);
    asm volatile("s_waitcnt vmcnt(4)" ::: "memory");  // A0,A1(t+1) landed
    BAR();
    asm volatile("s_waitcnt lgkmcnt(8)" ::: "memory");  // b23 landed
    __builtin_amdgcn_s_setprio(1);
    MFMA16(af_lo, 2, 0, 2);  // Q1: m0-3 x n2-3
    __builtin_amdgcn_s_setprio(0);

    // ---- P2: rd af_lo(t+1); stage A0(t+2) ----
    RD_AF(af_lo, Anx, 0);
    STAGE(t + 2, 0);
    BAR();
    asm volatile("s_waitcnt lgkmcnt(8)" ::: "memory");  // af_hi landed
    __builtin_amdgcn_s_setprio(1);
    MFMA16(af_hi, 2, 4, 2);  // Q2: m4-7 x n2-3
    __builtin_amdgcn_s_setprio(0);

    // ---- P3: stage A1(t+2); vmcnt(6) ----
    STAGE(t + 2, 1);
    asm volatile("s_waitcnt vmcnt(6)" ::: "memory");  // B1(t+1) landed
    BAR();
    __builtin_amdgcn_s_setprio(1);
    MFMA16(af_hi, 0, 4, 0);  // Q3: m4-7 x n0-1 (all resident)
    __builtin_amdgcn_s_setprio(0);
  }

  // epilogue: C/D layout col = l&15, row = 4*(l>>4)+j
  const int orow = tm * 256 + wr * 128 + ((l >> 4) << 2);
  const int ocol = tn * 256 + wc * 64 + (l & 15);
#pragma unroll
  for (int m = 0; m < 8; ++m)
#pragma unroll
    for (int n = 0; n < 4; ++n) {
      float* cp = C + (size_t)(orow + m * 16) * GN + (ocol + n * 16);
#pragma unroll
      for (int j = 0; j < 4; ++j) cp[(size_t)j * GN] = acc[m][n][j];
    }
}

extern "C" void kernel_launch(void* const* d_in, const int* in_sizes, int n_in,
                              void* d_out, int out_size, void* d_ws, size_t ws_size,
                              hipStream_t stream) {
  const float* x  = (const float*)d_in[0];
  const float* W  = (const float*)d_in[1];
  const float* lA = (const float*)d_in[2];
  const float* lB = (const float*)d_in[3];
  float* out = (float*)d_out;

  u16* weff = (u16*)d_ws;
  u16* xb = (u16*)((char*)d_ws + (size_t)GN * GK * sizeof(u16));

  build_weff<<<GN, 256, 0, stream>>>(W, lA, lB, weff);
  cvt_bf16<<<(size_t)GM * GK / (256 * 8), 256, 0, stream>>>(x, xb);
  gemm256<<<(GM / 256) * (GN / 256), 512, 0, stream>>>(xb, weff, out);
}